// Round 1
// baseline (67.859 us; speedup 1.0000x reference)
//
#include <hip/hip_runtime.h>

// RoIPool exactly matching the JAX reference:
//   x1 = int(W * box.x) (f32 multiply, trunc); sw = (x2-x1)/POOL (int div)
//   out[b,n,i,j,c] = max over s in [0,sh), t in [0,sw) of
//       fm[b, clip(y1+i*sh+s, 0, H-1), clip(x1+j*sw+t, 0, W-1), c]
// B=2, N=128, H=W=50, C=256, POOL=7.

#define POOLP 7
#define NROIS 128
#define HH 50
#define WW 50
#define CC 256

__global__ __launch_bounds__(256) void roipool_kernel(
    const float* __restrict__ fm,   // [B,H,W,C]
    const float* __restrict__ rpn,  // [B,N,4]
    float* __restrict__ out,        // [B,N,P,P,C]
    int total_vec)                  // B*N*P*P*(C/4)
{
    int tid = blockIdx.x * blockDim.x + threadIdx.x;
    if (tid >= total_vec) return;

    int cvec = tid & 63;        // which float4 within the 256 channels
    int cell = tid >> 6;        // flattened (b,n,i,j)
    int j = cell % POOLP;
    int tmp = cell / POOLP;
    int i = tmp % POOLP;
    tmp /= POOLP;
    int n = tmp % NROIS;
    int b = tmp / NROIS;

    const float* box = rpn + ((b * NROIS + n) << 2);
    int x1 = (int)(WW * box[0]);
    int y1 = (int)(HH * box[1]);
    int x2 = (int)(WW * box[2]);
    int y2 = (int)(HH * box[3]);
    int sw = (x2 - x1) / POOLP;
    int sh = (y2 - y1) / POOLP;

    const float NEG_INF = -__builtin_inff();
    float4 m = make_float4(NEG_INF, NEG_INF, NEG_INF, NEG_INF);
    int c0 = cvec << 2;

    for (int s = 0; s < sh; ++s) {
        int row = y1 + i * sh + s;
        row = min(max(row, 0), HH - 1);
        const float* rowp = fm + ((size_t)(b * HH + row) * WW) * CC;
        for (int t = 0; t < sw; ++t) {
            int col = x1 + j * sw + t;
            col = min(max(col, 0), WW - 1);
            float4 v = *reinterpret_cast<const float4*>(rowp + (size_t)col * CC + c0);
            m.x = fmaxf(m.x, v.x);
            m.y = fmaxf(m.y, v.y);
            m.z = fmaxf(m.z, v.z);
            m.w = fmaxf(m.w, v.w);
        }
    }

    reinterpret_cast<float4*>(out)[tid] = m;
}

extern "C" void kernel_launch(void* const* d_in, const int* in_sizes, int n_in,
                              void* d_out, int out_size, void* d_ws, size_t ws_size,
                              hipStream_t stream) {
    const float* fm  = (const float*)d_in[0];
    const float* rpn = (const float*)d_in[1];
    float* out = (float*)d_out;

    const int total_vec = 2 * NROIS * POOLP * POOLP * (CC / 4);  // 802816
    const int block = 256;
    const int grid = (total_vec + block - 1) / block;            // 3136
    roipool_kernel<<<grid, block, 0, stream>>>(fm, rpn, out, total_vec);
}